// Round 4
// baseline (259.823 us; speedup 1.0000x reference)
//
#include <hip/hip_runtime.h>
#include <math.h>

#define N_NODES 200000
#define NF 128
#define NT 32
#define NS 32
#define NG 128
#define SPLITS 16
#define TILE 64
#define XPAD 132   // x row stride (floats): odd multiple of 16B -> b128 reads conflict-benign
#define NHPAD 36   // nh row stride: bank=(4j+t)%32 distinct per lane -> conflict-free b32
#define HPAD 33    // hist/corr stride: bank=(t+s)%32 spreads across banks; slot 32 = dummy bin

__device__ __forceinline__ float rcp_fast(float x) { return __builtin_amdgcn_rcpf(x); }

__global__ __launch_bounds__(256, 3)
void ect_kernel(const float* __restrict__ x,
                const int* __restrict__ batch,   // int32 (JAX demotes int64)
                const float* __restrict__ v,
                float* __restrict__ out)
{
    __shared__ float    x_lds[TILE * XPAD];    // 33792 B
    __shared__ float    nh_lds[TILE * NHPAD];  //  9216 B
    __shared__ unsigned hist[NT * HPAD];       //  4224 B  step diff-array per (t, s_up)
    __shared__ float    corr[NT * HPAD];       //  4224 B  sigmoid-minus-step corrections
    // total ~51.5 KB -> 3 blocks/CU

    const int tid   = threadIdx.x;
    const int g     = blockIdx.x >> 4;
    const int split = blockIdx.x & (SPLITS - 1);

    // zero accumulators (harness poisons LDS)
    for (int i = tid; i < NT * HPAD; i += 256) { hist[i] = 0u; corr[i] = 0.0f; }
    __syncthreads();

    // graph range via binary search on sorted batch
    int lo = 0, hi = N_NODES;
    while (lo < hi) { int mid = (lo + hi) >> 1; if (batch[mid] < g) lo = mid + 1; else hi = mid; }
    const int g_start = lo;
    hi = N_NODES;
    while (lo < hi) { int mid = (lo + hi) >> 1; if (batch[mid] < g + 1) lo = mid + 1; else hi = mid; }
    const int g_end = lo;

    const int count = g_end - g_start;
    const int chunk = (count + SPLITS - 1) / SPLITS;
    int my_start = g_start + split * chunk;
    if (my_start > g_end) my_start = g_end;
    int my_end = my_start + chunk;
    if (my_end > g_end) my_end = g_end;
    const int my_count = my_end - my_start;

    const float inv_dlin = 14.090909090909092f;  // 31/2.2
    const float Lw       = 10.23848093f;         // SCALE * dlin * log2(e)
    const float dlin     = 2.2f / 31.0f;
    const float L        = 144.26950408889634f;  // SCALE * log2(e)

    // window-phase ownership: thread (r, t), r strides nodes
    const int t = tid & 31;
    const int r = tid >> 5;

    // matvec ownership: wave wu owns thetas [8wu, 8wu+8), lane = node
    const int node = tid & 63;
    const int wu = __builtin_amdgcn_readfirstlane(tid >> 6);
    const float* __restrict__ vbase = v + (size_t)wu * 8 * NF;

    for (int tile_start = my_start; tile_start < my_end; tile_start += TILE) {
        const int nvalid = min(TILE, my_end - tile_start);
        __syncthreads();   // protect LDS from previous iteration's readers

        // stage x tile (coalesced float4 global reads)
        #pragma unroll
        for (int j = 0; j < 8; ++j) {
            int idx4 = j * 256 + tid;
            int nn   = idx4 >> 5;
            int f4   = idx4 & 31;
            if (nn < nvalid) {
                float4 val = *(const float4*)&x[(size_t)(tile_start + nn) * NF + f4 * 4];
                *(float4*)&x_lds[nn * XPAD + f4 * 4] = val;
            }
        }
        __syncthreads();

        // nh = x . v^T : lane = node, 8 thetas, v via wave-uniform s_load
        if (node < nvalid) {
            float nh8[8] = {0.f,0.f,0.f,0.f,0.f,0.f,0.f,0.f};
            #pragma unroll 4
            for (int f4 = 0; f4 < 32; ++f4) {
                float4 xv = *(const float4*)&x_lds[node * XPAD + f4 * 4];
                #pragma unroll
                for (int tt = 0; tt < 8; ++tt) {
                    const float* vp = &vbase[tt * NF + f4 * 4];
                    nh8[tt] = fmaf(xv.x, vp[0], nh8[tt]);
                    nh8[tt] = fmaf(xv.y, vp[1], nh8[tt]);
                    nh8[tt] = fmaf(xv.z, vp[2], nh8[tt]);
                    nh8[tt] = fmaf(xv.w, vp[3], nh8[tt]);
                }
            }
            *(float4*)&nh_lds[node * NHPAD + wu * 8]     = make_float4(nh8[0], nh8[1], nh8[2], nh8[3]);
            *(float4*)&nh_lds[node * NHPAD + wu * 8 + 4] = make_float4(nh8[4], nh8[5], nh8[6], nh8[7]);
        }
        __syncthreads();

        // step-histogram + 3-wide sigmoid correction window per (node, t)
        for (int j = r; j < nvalid; j += 8) {
            float h = nh_lds[j * NHPAD + t];
            float z = fmaf(h, inv_dlin, 15.5f);          // (h + 1.1)/dlin
            int s_up = (int)ceilf(z);
            s_up = min(max(s_up, 0), 32);                // 32 = dummy bin (never read)
            atomicAdd(&hist[t * HPAD + s_up], 1u);       // all s >= s_up get +1 via prefix sum
            int s0 = (int)ceilf(z - 1.45f);
            #pragma unroll
            for (int i2 = 0; i2 < 3; ++i2) {
                int s = s0 + i2;
                // sigma = sigmoid(SCALE*(lin_s - h)) = 1/(1 + exp2(Lw*(z - s)))
                // saturation: exp2->inf gives rcp->0 (= sigma) so no predication needed
                float e   = __builtin_amdgcn_exp2f(Lw * (z - (float)s));
                float sig = rcp_fast(1.0f + e);
                float stp = (s >= s_up) ? 1.0f : 0.0f;
                float c   = sig - stp;
                if (s >= 0 && s <= 31) atomicAdd(&corr[t * HPAD + s], c);
            }
        }
    }
    __syncthreads();

    // prefix-sum the step histogram over s, fold into corr (thread t owns row t)
    if (tid < NT) {
        float run = 0.0f;
        for (int s = 0; s < NS; ++s) {
            run += (float)hist[tid * HPAD + s];
            corr[tid * HPAD + s] += run;
        }
    }
    __syncthreads();

    // write out, subtracting the constant pad term my_count * sigmoid(SCALE*(lin_s - R))
    const int sb = tid >> 5;
    #pragma unroll
    for (int k = 0; k < 4; ++k) {
        int s = sb + 8 * k;
        float lin_s = -1.1f + (float)s * dlin;
        float cs  = rcp_fast(1.0f + __builtin_amdgcn_exp2f(L * (1.1f - lin_s)));
        float val = corr[t * HPAD + s] - (float)my_count * cs;
        atomicAdd(&out[(size_t)g * (NS * NT) + s * NT + t], val);
    }
}

extern "C" void kernel_launch(void* const* d_in, const int* in_sizes, int n_in,
                              void* d_out, int out_size, void* d_ws, size_t ws_size,
                              hipStream_t stream) {
    const float* x     = (const float*)d_in[0];
    const int*   batch = (const int*)d_in[1];
    const float* v     = (const float*)d_in[3];
    float*       out   = (float*)d_out;

    hipMemsetAsync(d_out, 0, (size_t)out_size * sizeof(float), stream);
    ect_kernel<<<dim3(NG * SPLITS), dim3(256), 0, stream>>>(x, batch, v, out);
}

// Round 5
// 238.160 us; speedup vs baseline: 1.0910x; 1.0910x over previous
//
#include <hip/hip_runtime.h>
#include <math.h>

#define N_NODES 200000
#define NF 128
#define NT 32
#define NS 32
#define NG 128
#define SPLITS 32   // chunk = ceil(~1562/32) = ~49 <= TILE -> single tile pass per block
#define TILE 64
#define XPAD 132    // x row stride (floats): measured SQ_LDS_BANK_CONFLICT=0 with this layout
#define NHPAD 36    // nh row stride: conflict-free b32 reads
#define HPAD 33     // hist/corr stride; slot 32 = dummy overflow bin

__device__ __forceinline__ float rcp_fast(float x) { return __builtin_amdgcn_rcpf(x); }

// ---- pre-kernel: off[g] = first index i with batch[i] >= g (batch sorted) ----
__global__ __launch_bounds__(256)
void offsets_kernel(const int* __restrict__ batch, int* __restrict__ off)
{
    int i = blockIdx.x * 256 + threadIdx.x;
    if (i >= N_NODES) return;
    int b  = batch[i];
    int bp = (i == 0) ? -1 : batch[i - 1];
    for (int g = bp + 1; g <= b; ++g) off[g] = i;           // writes <= 129 total
    if (i == N_NODES - 1)
        for (int g = b + 1; g <= NG; ++g) off[g] = N_NODES; // trailing empty graphs
}

__global__ __launch_bounds__(256, 3)
void ect_kernel(const float* __restrict__ x,
                const float* __restrict__ v,
                const int* __restrict__ off,
                float* __restrict__ out)
{
    __shared__ float    x_lds[TILE * XPAD];    // 33792 B
    __shared__ float    nh_lds[TILE * NHPAD];  //  9216 B
    __shared__ unsigned hist[NT * HPAD];       //  4224 B
    __shared__ float    corr[NT * HPAD];       //  4224 B   ~51.5 KB -> 3 blocks/CU

    const int tid   = threadIdx.x;
    const int g     = blockIdx.x >> 5;
    const int split = blockIdx.x & (SPLITS - 1);

    for (int i = tid; i < NT * HPAD; i += 256) { hist[i] = 0u; corr[i] = 0.0f; }

    // graph range from precomputed offsets (2 loads instead of ~35-deep search)
    const int g_start = off[g];
    const int g_end   = off[g + 1];

    const int count = g_end - g_start;
    const int chunk = (count + SPLITS - 1) / SPLITS;
    int my_start = g_start + split * chunk;
    if (my_start > g_end) my_start = g_end;
    int my_end = my_start + chunk;
    if (my_end > g_end) my_end = g_end;
    const int my_count = my_end - my_start;

    const float inv_dlin = 14.090909090909092f;  // 31/2.2
    const float Lw       = 10.23848093f;         // SCALE * dlin * log2(e)
    const float dlin     = 2.2f / 31.0f;
    const float L        = 144.26950408889634f;  // SCALE * log2(e)

    const int t = tid & 31;
    const int r = tid >> 5;

    const int node = tid & 63;
    const int wu = __builtin_amdgcn_readfirstlane(tid >> 6);
    const float* __restrict__ vbase = v + (size_t)wu * 8 * NF;

    for (int tile_start = my_start; tile_start < my_end; tile_start += TILE) {
        const int nvalid = min(TILE, my_end - tile_start);
        __syncthreads();

        // stage x tile (coalesced float4 global reads)
        #pragma unroll
        for (int j = 0; j < 8; ++j) {
            int idx4 = j * 256 + tid;
            int nn   = idx4 >> 5;
            int f4   = idx4 & 31;
            if (nn < nvalid) {
                float4 val = *(const float4*)&x[(size_t)(tile_start + nn) * NF + f4 * 4];
                *(float4*)&x_lds[nn * XPAD + f4 * 4] = val;
            }
        }
        __syncthreads();

        // nh = x . v^T : lane = node, 8 thetas, v via wave-uniform s_load
        if (node < nvalid) {
            float nh8[8] = {0.f,0.f,0.f,0.f,0.f,0.f,0.f,0.f};
            #pragma unroll 4
            for (int f4 = 0; f4 < 32; ++f4) {
                float4 xv = *(const float4*)&x_lds[node * XPAD + f4 * 4];
                #pragma unroll
                for (int tt = 0; tt < 8; ++tt) {
                    const float* vp = &vbase[tt * NF + f4 * 4];
                    nh8[tt] = fmaf(xv.x, vp[0], nh8[tt]);
                    nh8[tt] = fmaf(xv.y, vp[1], nh8[tt]);
                    nh8[tt] = fmaf(xv.z, vp[2], nh8[tt]);
                    nh8[tt] = fmaf(xv.w, vp[3], nh8[tt]);
                }
            }
            *(float4*)&nh_lds[node * NHPAD + wu * 8]     = make_float4(nh8[0], nh8[1], nh8[2], nh8[3]);
            *(float4*)&nh_lds[node * NHPAD + wu * 8 + 4] = make_float4(nh8[4], nh8[5], nh8[6], nh8[7]);
        }
        __syncthreads();

        // step-histogram + 3-wide sigmoid correction per (node, t)
        for (int j = r; j < nvalid; j += 8) {
            float h = nh_lds[j * NHPAD + t];
            float z = fmaf(h, inv_dlin, 15.5f);          // (h + 1.1)/dlin
            int s_up = (int)ceilf(z);
            s_up = min(max(s_up, 0), 32);
            atomicAdd(&hist[t * HPAD + s_up], 1u);
            int s0 = (int)ceilf(z - 1.45f);
            #pragma unroll
            for (int i2 = 0; i2 < 3; ++i2) {
                int s = s0 + i2;
                float e   = __builtin_amdgcn_exp2f(Lw * (z - (float)s));
                float sig = rcp_fast(1.0f + e);
                float stp = (s >= s_up) ? 1.0f : 0.0f;
                float c   = sig - stp;
                if (s >= 0 && s <= 31) atomicAdd(&corr[t * HPAD + s], c);
            }
        }
    }
    __syncthreads();

    // prefix-sum step histogram over s, fold into corr
    if (tid < NT) {
        float run = 0.0f;
        for (int s = 0; s < NS; ++s) {
            run += (float)hist[tid * HPAD + s];
            corr[tid * HPAD + s] += run;
        }
    }
    __syncthreads();

    // flush, subtracting the constant pad term my_count * sigmoid(SCALE*(lin_s - R))
    const int sb = tid >> 5;
    #pragma unroll
    for (int k = 0; k < 4; ++k) {
        int s = sb + 8 * k;
        float lin_s = -1.1f + (float)s * dlin;
        float cs  = rcp_fast(1.0f + __builtin_amdgcn_exp2f(L * (1.1f - lin_s)));
        float val = corr[t * HPAD + s] - (float)my_count * cs;
        atomicAdd(&out[(size_t)g * (NS * NT) + s * NT + t], val);
    }
}

extern "C" void kernel_launch(void* const* d_in, const int* in_sizes, int n_in,
                              void* d_out, int out_size, void* d_ws, size_t ws_size,
                              hipStream_t stream) {
    const float* x     = (const float*)d_in[0];
    const int*   batch = (const int*)d_in[1];
    const float* v     = (const float*)d_in[3];
    float*       out   = (float*)d_out;
    int*         offs  = (int*)d_ws;   // 129 ints

    hipMemsetAsync(d_out, 0, (size_t)out_size * sizeof(float), stream);
    offsets_kernel<<<dim3((N_NODES + 255) / 256), dim3(256), 0, stream>>>(batch, offs);
    ect_kernel<<<dim3(NG * SPLITS), dim3(256), 0, stream>>>(x, v, offs, out);
}

// Round 6
// 198.458 us; speedup vs baseline: 1.3092x; 1.2001x over previous
//
#include <hip/hip_runtime.h>
#include <math.h>

#define N_NODES 200000
#define NF 128
#define NT 32
#define NS 32
#define NG 128
#define SPLITS 32
#define ATILE 64        // nodes per block in kernel A (200000 = 3125 * 64 exactly)
#define ABLOCKS 3125
#define KSTRIDE 136     // bf16 LDS row stride: 272 B = 16*17 -> b128-aligned, banks spread
#define HPAD 33         // hist/corr stride; slot 32 = dummy overflow bin

typedef short bf16x8 __attribute__((ext_vector_type(8)));
typedef float floatx4 __attribute__((ext_vector_type(4)));

__device__ __forceinline__ float rcp_fast(float x) { return __builtin_amdgcn_rcpf(x); }

// split fp32 into bf16 hi + bf16 lo (RTN both): x ~= hi + lo to ~2^-17 rel
__device__ __forceinline__ void split_bf16(float f, unsigned short& h, unsigned short& l) {
    unsigned u  = __float_as_uint(f);
    unsigned r  = u + 0x7FFFu + ((u >> 16) & 1u);
    unsigned hb = r & 0xFFFF0000u;
    h = (unsigned short)(hb >> 16);
    float rem = f - __uint_as_float(hb);
    unsigned u2 = __float_as_uint(rem);
    unsigned r2 = u2 + 0x7FFFu + ((u2 >> 16) & 1u);
    l = (unsigned short)(r2 >> 16);
}

// ---- offsets: off[g] = first i with batch[i] >= g ----
__global__ __launch_bounds__(256)
void offsets_kernel(const int* __restrict__ batch, int* __restrict__ off)
{
    int i = blockIdx.x * 256 + threadIdx.x;
    if (i >= N_NODES) return;
    int b  = batch[i];
    int bp = (i == 0) ? -1 : batch[i - 1];
    for (int g = bp + 1; g <= b; ++g) off[g] = i;
    if (i == N_NODES - 1)
        for (int g = b + 1; g <= NG; ++g) off[g] = N_NODES;
}

// ---- kernel A: nh[n][t] = sum_k x[n][k] * v[t][k], split-bf16 MFMA ----
__global__ __launch_bounds__(256, 2)
void gemm_kernel(const float* __restrict__ x,
                 const float* __restrict__ v,
                 float* __restrict__ nh)
{
    __shared__ unsigned short xh[ATILE * KSTRIDE];  // 17408 B
    __shared__ unsigned short xl[ATILE * KSTRIDE];  // 17408 B
    __shared__ unsigned short vh[NT * KSTRIDE];     //  8704 B
    __shared__ unsigned short vl[NT * KSTRIDE];     //  8704 B   ~52.2 KB -> 3 blocks/CU

    const int tid = threadIdx.x;
    const int blk = blockIdx.x;

    // stage x tile: 64 rows x 32 float4, convert to bf16 hi/lo
    #pragma unroll
    for (int j = 0; j < 8; ++j) {
        int idx4 = j * 256 + tid;
        int nn   = idx4 >> 5;
        int f4   = idx4 & 31;
        float4 val = *(const float4*)&x[(size_t)(blk * ATILE + nn) * NF + f4 * 4];
        unsigned short h0,h1,h2,h3,l0,l1,l2,l3;
        split_bf16(val.x, h0, l0); split_bf16(val.y, h1, l1);
        split_bf16(val.z, h2, l2); split_bf16(val.w, h3, l3);
        uint2 hh, ll;
        hh.x = (unsigned)h0 | ((unsigned)h1 << 16); hh.y = (unsigned)h2 | ((unsigned)h3 << 16);
        ll.x = (unsigned)l0 | ((unsigned)l1 << 16); ll.y = (unsigned)l2 | ((unsigned)l3 << 16);
        *(uint2*)&xh[nn * KSTRIDE + f4 * 4] = hh;
        *(uint2*)&xl[nn * KSTRIDE + f4 * 4] = ll;
    }
    // stage v: 32 rows x 32 float4
    #pragma unroll
    for (int j = 0; j < 4; ++j) {
        int idx4 = j * 256 + tid;
        int row  = idx4 >> 5;
        int f4   = idx4 & 31;
        float4 val = *(const float4*)&v[(size_t)row * NF + f4 * 4];
        unsigned short h0,h1,h2,h3,l0,l1,l2,l3;
        split_bf16(val.x, h0, l0); split_bf16(val.y, h1, l1);
        split_bf16(val.z, h2, l2); split_bf16(val.w, h3, l3);
        uint2 hh, ll;
        hh.x = (unsigned)h0 | ((unsigned)h1 << 16); hh.y = (unsigned)h2 | ((unsigned)h3 << 16);
        ll.x = (unsigned)l0 | ((unsigned)l1 << 16); ll.y = (unsigned)l2 | ((unsigned)l3 << 16);
        *(uint2*)&vh[row * KSTRIDE + f4 * 4] = hh;
        *(uint2*)&vl[row * KSTRIDE + f4 * 4] = ll;
    }
    __syncthreads();

    // wave w owns m-tile of 16 nodes; N=32 thetas = 2 n-tiles; K=128 = 4 slices
    const int w    = tid >> 6;
    const int lane = tid & 63;
    const int mrow = lane & 15;
    const int quad = lane >> 4;

    const int abase  = (w * 16 + mrow) * KSTRIDE + quad * 8;
    const int b0base = mrow * KSTRIDE + quad * 8;            // thetas 0..15
    const int b1base = (16 + mrow) * KSTRIDE + quad * 8;     // thetas 16..31

    floatx4 acc0 = {0.f, 0.f, 0.f, 0.f};
    floatx4 acc1 = {0.f, 0.f, 0.f, 0.f};

    #pragma unroll
    for (int slice = 0; slice < 4; ++slice) {
        bf16x8 ah  = *(bf16x8*)&xh[abase  + slice * 32];
        bf16x8 al  = *(bf16x8*)&xl[abase  + slice * 32];
        bf16x8 bh0 = *(bf16x8*)&vh[b0base + slice * 32];
        bf16x8 bl0 = *(bf16x8*)&vl[b0base + slice * 32];
        bf16x8 bh1 = *(bf16x8*)&vh[b1base + slice * 32];
        bf16x8 bl1 = *(bf16x8*)&vl[b1base + slice * 32];
        acc0 = __builtin_amdgcn_mfma_f32_16x16x32_bf16(ah, bh0, acc0, 0, 0, 0);
        acc0 = __builtin_amdgcn_mfma_f32_16x16x32_bf16(ah, bl0, acc0, 0, 0, 0);
        acc0 = __builtin_amdgcn_mfma_f32_16x16x32_bf16(al, bh0, acc0, 0, 0, 0);
        acc1 = __builtin_amdgcn_mfma_f32_16x16x32_bf16(ah, bh1, acc1, 0, 0, 0);
        acc1 = __builtin_amdgcn_mfma_f32_16x16x32_bf16(ah, bl1, acc1, 0, 0, 0);
        acc1 = __builtin_amdgcn_mfma_f32_16x16x32_bf16(al, bh1, acc1, 0, 0, 0);
    }

    // C/D layout: col(theta-in-tile) = lane&15, row(node-in-tile) = quad*4 + reg
    #pragma unroll
    for (int reg = 0; reg < 4; ++reg) {
        size_t node = (size_t)blk * ATILE + w * 16 + quad * 4 + reg;
        nh[node * NT + mrow]      = acc0[reg];
        nh[node * NT + 16 + mrow] = acc1[reg];
    }
}

// ---- kernel B: windowed sigmoid sweep over nh, per-graph accumulate ----
__global__ __launch_bounds__(256, 8)
void sweep_kernel(const float* __restrict__ nh,
                  const int* __restrict__ off,
                  float* __restrict__ out)
{
    __shared__ unsigned hist[NT * HPAD];   // 4224 B
    __shared__ float    corr[NT * HPAD];   // 4224 B  -> 8.5 KB, 8 blocks/CU (wave-capped)

    const int tid   = threadIdx.x;
    const int g     = blockIdx.x >> 5;
    const int split = blockIdx.x & (SPLITS - 1);

    for (int i = tid; i < NT * HPAD; i += 256) { hist[i] = 0u; corr[i] = 0.0f; }
    __syncthreads();

    const int g_start = off[g];
    const int g_end   = off[g + 1];
    const int count   = g_end - g_start;
    const int chunk   = (count + SPLITS - 1) / SPLITS;
    int my_start = g_start + split * chunk;
    if (my_start > g_end) my_start = g_end;
    int my_end = my_start + chunk;
    if (my_end > g_end) my_end = g_end;
    const int my_count = my_end - my_start;

    const float inv_dlin = 14.090909090909092f;  // 31/2.2
    const float Lw       = 10.23848093f;         // SCALE * dlin * log2(e)
    const float dlin     = 2.2f / 31.0f;
    const float L        = 144.26950408889634f;  // SCALE * log2(e)

    const int t = tid & 31;
    const int r = tid >> 5;

    // coalesced: 256 threads read 8 consecutive nh rows (128 B each) per iter
    for (int j = my_start + r; j < my_end; j += 8) {
        float h = nh[(size_t)j * NT + t];
        float z = fmaf(h, inv_dlin, 15.5f);      // (h + 1.1)/dlin
        int s_up = (int)ceilf(z);
        s_up = min(max(s_up, 0), 32);
        atomicAdd(&hist[t * HPAD + s_up], 1u);
        int s0 = (int)ceilf(z - 1.45f);
        #pragma unroll
        for (int i2 = 0; i2 < 3; ++i2) {
            int s = s0 + i2;
            float e   = __builtin_amdgcn_exp2f(Lw * (z - (float)s));
            float sig = rcp_fast(1.0f + e);
            float stp = (s >= s_up) ? 1.0f : 0.0f;
            float c   = sig - stp;
            if (s >= 0 && s <= 31) atomicAdd(&corr[t * HPAD + s], c);
        }
    }
    __syncthreads();

    // parallel inclusive prefix over s per row t: 8 shuffle-groups, 4 rows each
    {
        const int grp = tid >> 5;   // 0..7
        const int s   = tid & 31;
        for (int row = grp; row < NT; row += 8) {
            float val = (float)hist[row * HPAD + s];
            #pragma unroll
            for (int d = 1; d < 32; d <<= 1) {
                float nbr = __shfl_up(val, d, 32);
                if (s >= d) val += nbr;
            }
            corr[row * HPAD + s] += val;
        }
    }
    __syncthreads();

    // flush with exact pad-term subtraction: my_count * sigmoid(SCALE*(lin_s - R))
    const int sb = tid >> 5;
    #pragma unroll
    for (int k = 0; k < 4; ++k) {
        int s = sb + 8 * k;
        float lin_s = -1.1f + (float)s * dlin;
        float cs  = rcp_fast(1.0f + __builtin_amdgcn_exp2f(L * (1.1f - lin_s)));
        float val = corr[t * HPAD + s] - (float)my_count * cs;
        atomicAdd(&out[(size_t)g * (NS * NT) + s * NT + t], val);
    }
}

extern "C" void kernel_launch(void* const* d_in, const int* in_sizes, int n_in,
                              void* d_out, int out_size, void* d_ws, size_t ws_size,
                              hipStream_t stream) {
    const float* x     = (const float*)d_in[0];
    const int*   batch = (const int*)d_in[1];
    const float* v     = (const float*)d_in[3];
    float*       out   = (float*)d_out;

    int*   offs = (int*)d_ws;                          // 129 ints
    float* nh   = (float*)((char*)d_ws + 1024);        // 200000*32 fp32 = 25.6 MB

    hipMemsetAsync(d_out, 0, (size_t)out_size * sizeof(float), stream);
    offsets_kernel<<<dim3((N_NODES + 255) / 256), dim3(256), 0, stream>>>(batch, offs);
    gemm_kernel<<<dim3(ABLOCKS), dim3(256), 0, stream>>>(x, v, nh);
    sweep_kernel<<<dim3(NG * SPLITS), dim3(256), 0, stream>>>(nh, offs, out);
}

// Round 7
// 168.751 us; speedup vs baseline: 1.5397x; 1.1760x over previous
//
#include <hip/hip_runtime.h>
#include <math.h>

#define N_NODES 200000
#define NF 128
#define NT 32
#define NS 32
#define NG 128
#define ATILE 64        // nodes per block; 200000 = 3125 * 64 exactly
#define ABLOCKS 3125
#define VSTRIDE 136     // v LDS row stride in shorts: 272 B, 16B-aligned, 2-way banks (free)
#define HPAD 33         // hist/corr stride; slot 32 = dummy overflow bin

typedef short bf16x8 __attribute__((ext_vector_type(8)));
typedef float floatx4 __attribute__((ext_vector_type(4)));

__device__ __forceinline__ float rcp_fast(float x) { return __builtin_amdgcn_rcpf(x); }

// split fp32 into bf16 hi + bf16 lo (RTN both): f ~= hi + lo to ~2^-17 rel
__device__ __forceinline__ void split_bf16(float f, unsigned short& h, unsigned short& l) {
    unsigned u  = __float_as_uint(f);
    unsigned r  = u + 0x7FFFu + ((u >> 16) & 1u);
    unsigned hb = r & 0xFFFF0000u;
    h = (unsigned short)(hb >> 16);
    float rem = f - __uint_as_float(hb);
    unsigned u2 = __float_as_uint(rem);
    unsigned r2 = u2 + 0x7FFFu + ((u2 >> 16) & 1u);
    l = (unsigned short)(r2 >> 16);
}

__device__ __forceinline__ void split8(float4 a, float4 b, bf16x8& h8, bf16x8& l8) {
    unsigned short h[8], l[8];
    split_bf16(a.x, h[0], l[0]); split_bf16(a.y, h[1], l[1]);
    split_bf16(a.z, h[2], l[2]); split_bf16(a.w, h[3], l[3]);
    split_bf16(b.x, h[4], l[4]); split_bf16(b.y, h[5], l[5]);
    split_bf16(b.z, h[6], l[6]); split_bf16(b.w, h[7], l[7]);
    h8 = (bf16x8){(short)h[0],(short)h[1],(short)h[2],(short)h[3],
                  (short)h[4],(short)h[5],(short)h[6],(short)h[7]};
    l8 = (bf16x8){(short)l[0],(short)l[1],(short)l[2],(short)l[3],
                  (short)l[4],(short)l[5],(short)l[6],(short)l[7]};
}

__global__ __launch_bounds__(256, 4)
void ect_fused(const float* __restrict__ x,
               const int* __restrict__ batch,
               const float* __restrict__ v,
               float* __restrict__ out)
{
    __shared__ unsigned short vh[NT * VSTRIDE];  // 8704 B
    __shared__ unsigned short vl[NT * VSTRIDE];  // 8704 B
    __shared__ int      batch_lds[ATILE];        //  256 B
    __shared__ unsigned hist[NT * HPAD];         // 4224 B
    __shared__ float    corr[NT * HPAD];         // 4224 B
    __shared__ float    cnt_lds;                 // ~26.2 KB total -> 4 blocks/CU (VGPR-capped)

    const int tid  = threadIdx.x;
    const int blk  = blockIdx.x;
    const int w    = tid >> 6;
    const int lane = tid & 63;
    const int mrow = lane & 15;
    const int quad = lane >> 4;

    // ---- stage v -> bf16 hi/lo in LDS (32 rows x 32 float4) ----
    #pragma unroll
    for (int j = 0; j < 4; ++j) {
        int idx4 = j * 256 + tid;
        int row  = idx4 >> 5;
        int f4   = idx4 & 31;
        float4 val = *(const float4*)&v[(size_t)row * NF + f4 * 4];
        unsigned short h0,h1,h2,h3,l0,l1,l2,l3;
        split_bf16(val.x, h0, l0); split_bf16(val.y, h1, l1);
        split_bf16(val.z, h2, l2); split_bf16(val.w, h3, l3);
        uint2 hh, ll;
        hh.x = (unsigned)h0 | ((unsigned)h1 << 16); hh.y = (unsigned)h2 | ((unsigned)h3 << 16);
        ll.x = (unsigned)l0 | ((unsigned)l1 << 16); ll.y = (unsigned)l2 | ((unsigned)l3 << 16);
        *(uint2*)&vh[row * VSTRIDE + f4 * 4] = hh;
        *(uint2*)&vl[row * VSTRIDE + f4 * 4] = ll;
    }
    // stage this tile's batch labels
    if (tid < ATILE) batch_lds[tid] = batch[blk * ATILE + tid];

    // ---- A fragments straight from global: lane owns x row (w*16 + mrow) ----
    const size_t arow = (size_t)blk * ATILE + w * 16 + mrow;
    const float* __restrict__ xrow = x + arow * NF + quad * 8;

    floatx4 acc0 = {0.f, 0.f, 0.f, 0.f};   // thetas 0..15  (col = mrow)
    floatx4 acc1 = {0.f, 0.f, 0.f, 0.f};   // thetas 16..31

    bf16x8 ah[4], al[4];
    #pragma unroll
    for (int slice = 0; slice < 4; ++slice) {
        float4 a0 = *(const float4*)&xrow[slice * 32];
        float4 a1 = *(const float4*)&xrow[slice * 32 + 4];
        split8(a0, a1, ah[slice], al[slice]);
    }
    __syncthreads();   // vh/vl + batch_lds ready

    const int b0base = mrow * VSTRIDE + quad * 8;
    const int b1base = (16 + mrow) * VSTRIDE + quad * 8;
    #pragma unroll
    for (int slice = 0; slice < 4; ++slice) {
        bf16x8 bh0 = *(bf16x8*)&vh[b0base + slice * 32];
        bf16x8 bl0 = *(bf16x8*)&vl[b0base + slice * 32];
        bf16x8 bh1 = *(bf16x8*)&vh[b1base + slice * 32];
        bf16x8 bl1 = *(bf16x8*)&vl[b1base + slice * 32];
        acc0 = __builtin_amdgcn_mfma_f32_16x16x32_bf16(ah[slice], bh0, acc0, 0, 0, 0);
        acc0 = __builtin_amdgcn_mfma_f32_16x16x32_bf16(ah[slice], bl0, acc0, 0, 0, 0);
        acc0 = __builtin_amdgcn_mfma_f32_16x16x32_bf16(al[slice], bh0, acc0, 0, 0, 0);
        acc1 = __builtin_amdgcn_mfma_f32_16x16x32_bf16(ah[slice], bh1, acc1, 0, 0, 0);
        acc1 = __builtin_amdgcn_mfma_f32_16x16x32_bf16(ah[slice], bl1, acc1, 0, 0, 0);
        acc1 = __builtin_amdgcn_mfma_f32_16x16x32_bf16(al[slice], bh1, acc1, 0, 0, 0);
    }
    // C/D layout: col = lane&15 (theta), row = quad*4 + reg (node-in-16-tile)

    const float inv_dlin = 14.090909090909092f;  // 31/2.2
    const float Lw       = 10.23848093f;         // SCALE * dlin * log2(e)
    const float dlin     = 2.2f / 31.0f;
    const float L        = 144.26950408889634f;  // SCALE * log2(e)

    const int g_first = batch_lds[0];
    const int g_last  = batch_lds[ATILE - 1];

    // flush ownership: thread -> (t, s = sb + 8k)
    const int ft = tid & 31;
    const int sb = tid >> 5;

    for (int gp = g_first; gp <= g_last; ++gp) {   // 96% of tiles: single pass
        for (int i = tid; i < NT * HPAD; i += 256) { hist[i] = 0u; corr[i] = 0.0f; }
        __syncthreads();

        // sweep directly on the accumulator (C-layout): lane owns 4 nodes x 2 thetas
        #pragma unroll
        for (int reg = 0; reg < 4; ++reg) {
            int n = w * 16 + quad * 4 + reg;
            if (batch_lds[n] == gp) {
                #pragma unroll
                for (int half = 0; half < 2; ++half) {
                    int   t = half ? (16 + mrow) : mrow;
                    float h = half ? acc1[reg] : acc0[reg];
                    float z = fmaf(h, inv_dlin, 15.5f);      // (h + 1.1)/dlin
                    int s_up = (int)ceilf(z);
                    s_up = min(max(s_up, 0), 32);
                    atomicAdd(&hist[t * HPAD + s_up], 1u);
                    int s0 = (int)ceilf(z - 1.45f);
                    #pragma unroll
                    for (int i2 = 0; i2 < 3; ++i2) {
                        int s = s0 + i2;
                        float e   = __builtin_amdgcn_exp2f(Lw * (z - (float)s));
                        float sig = rcp_fast(1.0f + e);
                        float stp = (s >= s_up) ? 1.0f : 0.0f;
                        if (s >= 0 && s <= 31) atomicAdd(&corr[t * HPAD + s], sig - stp);
                    }
                }
            }
        }
        __syncthreads();

        // node count for this graph in tile (wave 0) + prefix-scan hist into corr
        if (tid < ATILE) {
            unsigned long long m = __ballot(batch_lds[tid] == gp);
            if (tid == 0) cnt_lds = (float)__popcll(m);
        }
        {
            const int grp = tid >> 5;   // 8 groups x 32 lanes; group handles rows grp+8i
            const int s   = tid & 31;
            for (int row = grp; row < NT; row += 8) {
                float val = (float)hist[row * HPAD + s];
                #pragma unroll
                for (int d = 1; d < 32; d <<= 1) {
                    float nbr = __shfl_up(val, d, 32);
                    if (s >= d) val += nbr;
                }
                corr[row * HPAD + s] += val;
            }
        }
        __syncthreads();

        // flush: subtract exact pad term cnt * sigmoid(SCALE*(lin_s - R))
        #pragma unroll
        for (int k = 0; k < 4; ++k) {
            int s = sb + 8 * k;
            float lin_s = -1.1f + (float)s * dlin;
            float cs  = rcp_fast(1.0f + __builtin_amdgcn_exp2f(L * (1.1f - lin_s)));
            float val = corr[ft * HPAD + s] - cnt_lds * cs;
            atomicAdd(&out[(size_t)gp * (NS * NT) + s * NT + ft], val);
        }
        if (gp < g_last) __syncthreads();
    }
}

extern "C" void kernel_launch(void* const* d_in, const int* in_sizes, int n_in,
                              void* d_out, int out_size, void* d_ws, size_t ws_size,
                              hipStream_t stream) {
    const float* x     = (const float*)d_in[0];
    const int*   batch = (const int*)d_in[1];
    const float* v     = (const float*)d_in[3];
    float*       out   = (float*)d_out;

    hipMemsetAsync(d_out, 0, (size_t)out_size * sizeof(float), stream);
    ect_fused<<<dim3(ABLOCKS), dim3(256), 0, stream>>>(x, batch, v, out);
}